// Round 6
// baseline (381.437 us; speedup 1.0000x reference)
//
#include <hip/hip_runtime.h>
#include <stdint.h>

#define D_DIM 512

typedef __attribute__((ext_vector_type(8))) short bf16x8;
typedef __attribute__((ext_vector_type(4))) float f32x4;
typedef __attribute__((ext_vector_type(4))) short short4_t;
typedef __attribute__((ext_vector_type(4))) float float4_t;

__device__ __forceinline__ unsigned short f2bf(float f) {
  unsigned u = __float_as_uint(f);
  u += 0x7FFFu + ((u >> 16) & 1u);
  return (unsigned short)(u >> 16);
}

__device__ __forceinline__ float bf2f(unsigned short s) {
  return __uint_as_float(((unsigned)s) << 16);
}

__device__ __forceinline__ float tanh_fast(float x) {
  float e = __expf(2.0f * x);
  return 1.0f - 2.0f / (e + 1.0f);
}

// ---------------- small utility kernels ----------------

__global__ void cvt_f32_bf16_k(const float* __restrict__ in, unsigned short* __restrict__ out, int n4) {
  int i = blockIdx.x * blockDim.x + threadIdx.x;
  if (i < n4) {
    float4_t v = ((const float4_t*)in)[i];
    short4_t s;
    s.x = (short)f2bf(v.x); s.y = (short)f2bf(v.y);
    s.z = (short)f2bf(v.z); s.w = (short)f2bf(v.w);
    ((short4_t*)out)[i] = s;
  }
}

// converts 3 equally-sized f32 buffers into one contiguous bf16 region
__global__ void cvt3_f32_bf16_k(const float* __restrict__ a, const float* __restrict__ b,
                                const float* __restrict__ c, unsigned short* __restrict__ out,
                                int n4each) {
  int i = blockIdx.x * blockDim.x + threadIdx.x;
  if (i >= 3 * n4each) return;
  int sel = i / n4each, j = i - sel * n4each;
  const float* src = (sel == 0) ? a : (sel == 1) ? b : c;
  float4_t v = ((const float4_t*)src)[j];
  short4_t s;
  s.x = (short)f2bf(v.x); s.y = (short)f2bf(v.y);
  s.z = (short)f2bf(v.z); s.w = (short)f2bf(v.w);
  ((short4_t*)out)[i] = s;
}

__global__ void prep_cluster_k(const int* __restrict__ vn, const int* __restrict__ nid,
                               int* __restrict__ cl, int* __restrict__ counts, int B) {
  int i = blockIdx.x * blockDim.x + threadIdx.x;
  if (i < B) {
    int c = vn[2 * nid[i] + 1];
    cl[i] = c;
    atomicAdd(&counts[c], 1);
  }
}

__global__ void prefix_k(const int* __restrict__ counts, int* __restrict__ starts,
                         int* __restrict__ cursor, int C) {
  __shared__ int sh[1024];
  int t = threadIdx.x;
  int v = (t < C) ? counts[t] : 0;
  sh[t] = v;
  __syncthreads();
  for (int off = 1; off < 1024; off <<= 1) {
    int x = (t >= off) ? sh[t - off] : 0;
    __syncthreads();
    sh[t] += x;
    __syncthreads();
  }
  if (t < C) { int st = sh[t] - v; starts[t] = st; cursor[t] = st; }
  if (t == 1023) starts[C] = sh[1023];
}

__global__ void scatter_k(const int* __restrict__ cl, int* __restrict__ cursor,
                          int* __restrict__ order, int B) {
  int i = blockIdx.x * blockDim.x + threadIdx.x;
  if (i < B) {
    int pos = atomicAdd(&cursor[cl[i]], 1);
    order[pos] = i;
  }
}

__device__ __forceinline__ unsigned enc_f(float f) {
  unsigned u = __float_as_uint(f);
  return (u & 0x80000000u) ? ~u : (u | 0x80000000u);
}
__device__ __forceinline__ float dec_f(unsigned u) {
  return __uint_as_float((u & 0x80000000u) ? (u & 0x7FFFFFFFu) : ~u);
}

__global__ void seg_max_k(const float* __restrict__ score, const int* __restrict__ cl,
                          unsigned* __restrict__ smax, int B) {
  int i = blockIdx.x * blockDim.x + threadIdx.x;
  if (i < B) atomicMax(&smax[cl[i]], enc_f(score[i]));
}

__global__ void seg_expsum_k(const float* __restrict__ score, const int* __restrict__ cl,
                             const unsigned* __restrict__ smax, float* __restrict__ ev,
                             float* __restrict__ denom, int B) {
  int i = blockIdx.x * blockDim.x + threadIdx.x;
  if (i < B) {
    int c = cl[i];
    float x = __expf(score[i] - dec_f(smax[c]));
    ev[i] = x;
    atomicAdd(&denom[c], x);
  }
}

// 256 threads; thread t owns d = 2t, 2t+1 (one uint = 2 bf16 per row); 4-row unroll
__global__ __launch_bounds__(256)
void ctx_k(const unsigned short* __restrict__ hbf, const float* __restrict__ ev,
           const int* __restrict__ order, const int* __restrict__ starts,
           const float* __restrict__ denom, float* __restrict__ ctx) {
  int c = blockIdx.x;
  int t = threadIdx.x;
  int s0 = starts[c], s1 = starts[c + 1];
  float a0 = 0.f, a1 = 0.f;
  int j = s0;
  for (; j + 3 < s1; j += 4) {
    int i0 = order[j], i1 = order[j + 1], i2 = order[j + 2], i3 = order[j + 3];
    float e0 = ev[i0], e1 = ev[i1], e2 = ev[i2], e3 = ev[i3];
    unsigned u0 = *(const unsigned*)(hbf + (size_t)i0 * D_DIM + t * 2);
    unsigned u1 = *(const unsigned*)(hbf + (size_t)i1 * D_DIM + t * 2);
    unsigned u2 = *(const unsigned*)(hbf + (size_t)i2 * D_DIM + t * 2);
    unsigned u3 = *(const unsigned*)(hbf + (size_t)i3 * D_DIM + t * 2);
    a0 += e0 * bf2f((unsigned short)u0) + e1 * bf2f((unsigned short)u1)
        + e2 * bf2f((unsigned short)u2) + e3 * bf2f((unsigned short)u3);
    a1 += e0 * bf2f((unsigned short)(u0 >> 16)) + e1 * bf2f((unsigned short)(u1 >> 16))
        + e2 * bf2f((unsigned short)(u2 >> 16)) + e3 * bf2f((unsigned short)(u3 >> 16));
  }
  for (; j < s1; ++j) {
    int i0 = order[j];
    float e0 = ev[i0];
    unsigned u0 = *(const unsigned*)(hbf + (size_t)i0 * D_DIM + t * 2);
    a0 += e0 * bf2f((unsigned short)u0);
    a1 += e0 * bf2f((unsigned short)(u0 >> 16));
  }
  float inv = 1.0f / denom[c];
  float2 r = make_float2(a0 * inv, a1 * inv);
  *(float2*)(&ctx[(size_t)c * D_DIM + t * 2]) = r;
}

// ------ ZERO-LDS bf16 MFMA GEMM: 128x128 per block, fragments direct from L2 ------
// A: [M][512] bf16, Bw: [512][512] bf16 (row n = output col n)
// 1D grid = 4 * ceil(M/128), XCD-chunked swizzle; 256 threads (4 waves, 2x2 of 64x64).
// No LDS staging, no barriers in the K-loop: each lane global-loads its MFMA
// fragments (16B dwordx4, naturally the fragment layout) with an explicit
// 1-step register prefetch; B (512KB) is L2-resident per XCD, A streams from
// HBM shared via L2 by the 4 N-sibling blocks. ~12 waves/CU cover the latency:
// per-CU MFMA demand/step (~930 cy) ~ HBM latency (~900 cy).
// EPI 0: out[m][n] = acc + bias[n]
// EPI 1: atomicAdd(out[m], sum_n tanh(acc + qb[cl[m]][n]) * Ws[n])
// EPI 2: out[m][n] = tanh(acc + bias[n])
template<int EPI>
__global__ __launch_bounds__(256, 3)
void gemm128_reg_k(const unsigned short* __restrict__ Abf,
                   const unsigned short* __restrict__ Bw, int M,
                   const float* __restrict__ qb, const int* __restrict__ cl,
                   const float* __restrict__ Ws, const float* __restrict__ bias,
                   float* __restrict__ out)
{
  const int t = threadIdx.x;
  const int lane = t & 63;
  const int w = t >> 6;             // wave 0..3
  const int wr = w >> 1, wc = w & 1;
  const int l15 = lane & 15, l4 = lane >> 4;

  // XCD-chunked swizzle (bijective: gridDim.x % 8 == 0 for all our grids)
  const int nwg = gridDim.x;
  int id = blockIdx.x;
  if ((nwg & 7) == 0) id = (id & 7) * (nwg >> 3) + (id >> 3);
  const int n0 = (id & 3) * 128;    // n-block fastest -> siblings adjacent on one XCD
  const int m0 = (id >> 2) * 128;

  // per-lane fragment base pointers; K-step advances by imm offset (<=960B)
  const unsigned short* aP[4];
  const unsigned short* bP[4];
  #pragma unroll
  for (int mi = 0; mi < 4; ++mi) {
    int row = m0 + wr * 64 + mi * 16 + l15; if (row > M - 1) row = M - 1;
    aP[mi] = Abf + (size_t)row * 512 + l4 * 8;
  }
  #pragma unroll
  for (int ni = 0; ni < 4; ++ni) {
    int col = n0 + wc * 64 + ni * 16 + l15;
    bP[ni] = Bw + (size_t)col * 512 + l4 * 8;
  }

  f32x4 acc[4][4];
  #pragma unroll
  for (int mi = 0; mi < 4; ++mi)
    #pragma unroll
    for (int ni = 0; ni < 4; ++ni)
      acc[mi][ni] = (f32x4){0.f, 0.f, 0.f, 0.f};

  // 1-step register prefetch pipeline; indices constant after full unroll
  bf16x8 af[2][4], bfv[2][4];
  #pragma unroll
  for (int mi = 0; mi < 4; ++mi) af[0][mi] = *(const bf16x8*)(aP[mi]);
  #pragma unroll
  for (int ni = 0; ni < 4; ++ni) bfv[0][ni] = *(const bf16x8*)(bP[ni]);

  #pragma unroll
  for (int it = 0; it < 16; ++it) {
    const int cur = it & 1, nxt = cur ^ 1;
    if (it < 15) {
      const int k1 = (it + 1) * 32;   // elements; folds into load imm offset
      #pragma unroll
      for (int mi = 0; mi < 4; ++mi) af[nxt][mi] = *(const bf16x8*)(aP[mi] + k1);
      #pragma unroll
      for (int ni = 0; ni < 4; ++ni) bfv[nxt][ni] = *(const bf16x8*)(bP[ni] + k1);
    }
    #pragma unroll
    for (int mi = 0; mi < 4; ++mi)
      #pragma unroll
      for (int ni = 0; ni < 4; ++ni)
        acc[mi][ni] = __builtin_amdgcn_mfma_f32_16x16x32_bf16(af[cur][mi], bfv[cur][ni], acc[mi][ni], 0, 0, 0);
  }

  if (EPI == 0 || EPI == 2) {
    #pragma unroll
    for (int mi = 0; mi < 4; ++mi) {
      #pragma unroll
      for (int r = 0; r < 4; ++r) {
        int gm = m0 + wr * 64 + mi * 16 + l4 * 4 + r;
        if (gm < M) {
          #pragma unroll
          for (int ni = 0; ni < 4; ++ni) {
            int gcol = n0 + wc * 64 + ni * 16 + l15;
            float v = acc[mi][ni][r] + bias[gcol];
            if (EPI == 2) v = tanh_fast(v);
            out[(size_t)gm * 512 + gcol] = v;
          }
        }
      }
    }
  } else {
    // fused additive-attention partial score over this block's 128 cols
    __shared__ float red[128][2];
    __shared__ int clds[128];
    if (t < 128) {
      int gm = m0 + t;
      clds[t] = (gm < M) ? cl[gm] : 0;
    }
    __syncthreads();
    #pragma unroll
    for (int mi = 0; mi < 4; ++mi) {
      #pragma unroll
      for (int r = 0; r < 4; ++r) {
        int rowt = wr * 64 + mi * 16 + l4 * 4 + r;
        int c = clds[rowt];
        const float* qrow = &qb[(size_t)c * 512 + n0 + wc * 64];
        float s = 0.f;
        #pragma unroll
        for (int ni = 0; ni < 4; ++ni) {
          int colw = ni * 16 + l15;
          float x = acc[mi][ni][r] + qrow[colw];
          s += tanh_fast(x) * Ws[n0 + wc * 64 + colw];
        }
        s += __shfl_xor(s, 1);
        s += __shfl_xor(s, 2);
        s += __shfl_xor(s, 4);
        s += __shfl_xor(s, 8);
        if (l15 == 0) red[rowt][wc] = s;
      }
    }
    __syncthreads();
    if (t < 128) {
      int gm = m0 + t;
      if (gm < M) atomicAdd(&out[gm], red[t][0] + red[t][1]);
    }
  }
}

// ---------------- host side ----------------

extern "C" void kernel_launch(void* const* d_in, const int* in_sizes, int n_in,
                              void* d_out, int out_size, void* d_ws, size_t ws_size,
                              hipStream_t stream) {
  const float* h  = (const float*)d_in[0];
  const float* g  = (const float*)d_in[1];
  const int*   vn = (const int*)d_in[2];
  const int*   nid= (const int*)d_in[3];
  const float* Wq = (const float*)d_in[4];
  const float* Wk = (const float*)d_in[5];
  const float* ab = (const float*)d_in[6];
  const float* Ws = (const float*)d_in[7];
  const float* W  = (const float*)d_in[9];
  const float* b  = (const float*)d_in[10];

  const int B = in_sizes[3];          // 100000
  const int C = in_sizes[1] / D_DIM;  // 1000

  char* wsb = (char*)d_ws;
  size_t off = 0;
  auto alloc = [&](size_t bytes) -> void* {
    void* p = wsb + off;
    off += (bytes + 255) & ~(size_t)255;
    return p;
  };

  unsigned short* hbf   = (unsigned short*)alloc((size_t)B * 512 * 2);
  unsigned short* gbf   = (unsigned short*)alloc((size_t)C * 512 * 2);
  unsigned short* ctxbf = (unsigned short*)alloc((size_t)C * 512 * 2);
  unsigned short* Wk_bf = (unsigned short*)alloc((size_t)512 * 512 * 2);  // contiguous
  unsigned short* Wq_bf = (unsigned short*)alloc((size_t)512 * 512 * 2);  // with Wk_bf
  unsigned short* W_bf  = (unsigned short*)alloc((size_t)512 * 512 * 2);  // and Wq_bf
  float* qb    = (float*)alloc((size_t)C * 512 * 4);
  float* ctx   = (float*)alloc((size_t)C * 512 * 4);
  float* score = (float*)alloc((size_t)B * 4);
  float* ev    = (float*)alloc((size_t)B * 4);
  int*   cl    = (int*)alloc((size_t)B * 4);
  int*   order = (int*)alloc((size_t)B * 4);
  int*      counts = (int*)alloc((size_t)C * 4);
  unsigned* smax   = (unsigned*)alloc((size_t)C * 4);
  float*    denom  = (float*)alloc((size_t)C * 4);
  int* starts = (int*)alloc((size_t)(C + 1) * 4);
  int* cursor = (int*)alloc((size_t)C * 4);
  (void)ws_size; (void)n_in; (void)out_size;

  // zero atomically-accumulated buffers each launch
  size_t zlen = (size_t)((char*)denom - (char*)counts) + (size_t)C * 4;
  hipMemsetAsync(counts, 0, zlen, stream);
  hipMemsetAsync(score, 0, (size_t)B * 4, stream);

  // conversions
  cvt_f32_bf16_k<<<(B * 512 / 4 + 255) / 256, 256, 0, stream>>>(h, hbf, B * 512 / 4);
  cvt_f32_bf16_k<<<(C * 512 / 4 + 255) / 256, 256, 0, stream>>>(g, gbf, C * 512 / 4);
  const int n4w = 512 * 512 / 4;
  cvt3_f32_bf16_k<<<(3 * n4w + 255) / 256, 256, 0, stream>>>(Wk, Wq, W, Wk_bf, n4w);

  prep_cluster_k<<<(B + 255) / 256, 256, 0, stream>>>(vn, nid, cl, counts, B);
  prefix_k<<<1, 1024, 0, stream>>>(counts, starts, cursor, C);
  scatter_k<<<(B + 255) / 256, 256, 0, stream>>>(cl, cursor, order, B);

  // qb = g @ Wq^T + attn_bias
  gemm128_reg_k<0><<<4 * ((C + 127) / 128), 256, 0, stream>>>(
      gbf, Wq_bf, C, nullptr, nullptr, nullptr, ab, qb);

  // score[m] += sum over this N-block of tanh(h@Wk^T + qb[cl])·Ws  (bs dropped:
  // softmax is invariant to a constant shift)
  gemm128_reg_k<1><<<4 * ((B + 127) / 128), 256, 0, stream>>>(
      hbf, Wk_bf, B, qb, cl, Ws, nullptr, score);

  seg_max_k<<<(B + 255) / 256, 256, 0, stream>>>(score, cl, smax, B);
  seg_expsum_k<<<(B + 255) / 256, 256, 0, stream>>>(score, cl, smax, ev, denom, B);
  ctx_k<<<C, 256, 0, stream>>>(hbf, ev, order, starts, denom, ctx);

  cvt_f32_bf16_k<<<(C * 512 / 4 + 255) / 256, 256, 0, stream>>>(ctx, ctxbf, C * 512 / 4);

  // out = tanh(ctx @ W^T + b)
  gemm128_reg_k<2><<<4 * ((C + 127) / 128), 256, 0, stream>>>(
      ctxbf, W_bf, C, nullptr, nullptr, nullptr, b, (float*)d_out);
}

// Round 7
// 248.821 us; speedup vs baseline: 1.5330x; 1.5330x over previous
//
#include <hip/hip_runtime.h>
#include <stdint.h>

#define D_DIM 512

typedef __attribute__((ext_vector_type(8))) short bf16x8;
typedef __attribute__((ext_vector_type(4))) float f32x4;
typedef __attribute__((ext_vector_type(4))) short short4_t;
typedef __attribute__((ext_vector_type(4))) float float4_t;

__device__ __forceinline__ unsigned short f2bf(float f) {
  unsigned u = __float_as_uint(f);
  u += 0x7FFFu + ((u >> 16) & 1u);
  return (unsigned short)(u >> 16);
}

__device__ __forceinline__ float bf2f(unsigned short s) {
  return __uint_as_float(((unsigned)s) << 16);
}

__device__ __forceinline__ float tanh_fast(float x) {
  float e = __expf(2.0f * x);
  return 1.0f - 2.0f / (e + 1.0f);
}

#define GLOAD_LDS16(gsrc, ldst) \
  __builtin_amdgcn_global_load_lds((const __attribute__((address_space(1))) void*)(gsrc), \
                                   (__attribute__((address_space(3))) void*)(ldst), 16, 0, 0)

// ---------------- small utility kernels ----------------

__global__ void cvt_f32_bf16_k(const float* __restrict__ in, unsigned short* __restrict__ out, int n4) {
  int i = blockIdx.x * blockDim.x + threadIdx.x;
  if (i < n4) {
    float4_t v = ((const float4_t*)in)[i];
    short4_t s;
    s.x = (short)f2bf(v.x); s.y = (short)f2bf(v.y);
    s.z = (short)f2bf(v.z); s.w = (short)f2bf(v.w);
    ((short4_t*)out)[i] = s;
  }
}

__global__ void cvt3_f32_bf16_k(const float* __restrict__ a, const float* __restrict__ b,
                                const float* __restrict__ c, unsigned short* __restrict__ out,
                                int n4each) {
  int i = blockIdx.x * blockDim.x + threadIdx.x;
  if (i >= 3 * n4each) return;
  int sel = i / n4each, j = i - sel * n4each;
  const float* src = (sel == 0) ? a : (sel == 1) ? b : c;
  float4_t v = ((const float4_t*)src)[j];
  short4_t s;
  s.x = (short)f2bf(v.x); s.y = (short)f2bf(v.y);
  s.z = (short)f2bf(v.z); s.w = (short)f2bf(v.w);
  ((short4_t*)out)[i] = s;
}

__global__ void prep_cluster_k(const int* __restrict__ vn, const int* __restrict__ nid,
                               int* __restrict__ cl, int* __restrict__ counts, int B) {
  int i = blockIdx.x * blockDim.x + threadIdx.x;
  if (i < B) {
    int c = vn[2 * nid[i] + 1];
    cl[i] = c;
    atomicAdd(&counts[c], 1);
  }
}

__global__ void prefix_k(const int* __restrict__ counts, int* __restrict__ starts,
                         int* __restrict__ cursor, int C) {
  __shared__ int sh[1024];
  int t = threadIdx.x;
  int v = (t < C) ? counts[t] : 0;
  sh[t] = v;
  __syncthreads();
  for (int off = 1; off < 1024; off <<= 1) {
    int x = (t >= off) ? sh[t - off] : 0;
    __syncthreads();
    sh[t] += x;
    __syncthreads();
  }
  if (t < C) { int st = sh[t] - v; starts[t] = st; cursor[t] = st; }
  if (t == 1023) starts[C] = sh[1023];
}

__global__ void scatter_k(const int* __restrict__ cl, int* __restrict__ cursor,
                          int* __restrict__ order, int B) {
  int i = blockIdx.x * blockDim.x + threadIdx.x;
  if (i < B) {
    int pos = atomicAdd(&cursor[cl[i]], 1);
    order[pos] = i;
  }
}

__device__ __forceinline__ unsigned enc_f(float f) {
  unsigned u = __float_as_uint(f);
  return (u & 0x80000000u) ? ~u : (u | 0x80000000u);
}
__device__ __forceinline__ float dec_f(unsigned u) {
  return __uint_as_float((u & 0x80000000u) ? (u & 0x7FFFFFFFu) : ~u);
}

__global__ void seg_max_k(const float* __restrict__ score, const int* __restrict__ cl,
                          unsigned* __restrict__ smax, int B) {
  int i = blockIdx.x * blockDim.x + threadIdx.x;
  if (i < B) atomicMax(&smax[cl[i]], enc_f(score[i]));
}

__global__ void seg_expsum_k(const float* __restrict__ score, const int* __restrict__ cl,
                             const unsigned* __restrict__ smax, float* __restrict__ ev,
                             float* __restrict__ denom, int B) {
  int i = blockIdx.x * blockDim.x + threadIdx.x;
  if (i < B) {
    int c = cl[i];
    float x = __expf(score[i] - dec_f(smax[c]));
    ev[i] = x;
    atomicAdd(&denom[c], x);
  }
}

__global__ __launch_bounds__(256)
void ctx_k(const unsigned short* __restrict__ hbf, const float* __restrict__ ev,
           const int* __restrict__ order, const int* __restrict__ starts,
           const float* __restrict__ denom, float* __restrict__ ctx) {
  int c = blockIdx.x;
  int t = threadIdx.x;
  int s0 = starts[c], s1 = starts[c + 1];
  float a0 = 0.f, a1 = 0.f;
  int j = s0;
  for (; j + 3 < s1; j += 4) {
    int i0 = order[j], i1 = order[j + 1], i2 = order[j + 2], i3 = order[j + 3];
    float e0 = ev[i0], e1 = ev[i1], e2 = ev[i2], e3 = ev[i3];
    unsigned u0 = *(const unsigned*)(hbf + (size_t)i0 * D_DIM + t * 2);
    unsigned u1 = *(const unsigned*)(hbf + (size_t)i1 * D_DIM + t * 2);
    unsigned u2 = *(const unsigned*)(hbf + (size_t)i2 * D_DIM + t * 2);
    unsigned u3 = *(const unsigned*)(hbf + (size_t)i3 * D_DIM + t * 2);
    a0 += e0 * bf2f((unsigned short)u0) + e1 * bf2f((unsigned short)u1)
        + e2 * bf2f((unsigned short)u2) + e3 * bf2f((unsigned short)u3);
    a1 += e0 * bf2f((unsigned short)(u0 >> 16)) + e1 * bf2f((unsigned short)(u1 >> 16))
        + e2 * bf2f((unsigned short)(u2 >> 16)) + e3 * bf2f((unsigned short)(u3 >> 16));
  }
  for (; j < s1; ++j) {
    int i0 = order[j];
    float e0 = ev[i0];
    unsigned u0 = *(const unsigned*)(hbf + (size_t)i0 * D_DIM + t * 2);
    a0 += e0 * bf2f((unsigned short)u0);
    a1 += e0 * bf2f((unsigned short)(u0 >> 16));
  }
  float inv = 1.0f / denom[c];
  float2 r = make_float2(a0 * inv, a1 * inv);
  *(float2*)(&ctx[(size_t)c * D_DIM + t * 2]) = r;
}

// ====== 256x256-tile score GEMM (EPI1 of old kernel), BK=64, 8 waves ======
// A: [M][512] bf16, Bw: [512][512] bf16 (row n = output col n). Grid = 2*ceil(M/256),
// bijective XCD-chunked swizzle. Wave w: wr=w>>2 (M half), wc=w&3 (64-col slice);
// per-wave output 128x64 -> acc[8][4] f32x4.
// LDS: A,B double-buffered [256][64] bf16 tiles (32KB each); rows are 128B = 8
// 16B slots, swizzled phys_slot = slot ^ (row&7) (R2-R4: measured 0 conflicts).
// global_load_lds writes linearly; SOURCE address carries the inverse swizzle.
// Schedule per K-tile t (two phases ks=0,1, 32 MFMA each):
//   [vmcnt(0) - t's loads issued >=1 phase (~1200cy) ago - + s_barrier]
//   ph0: ds_read a[8],b[4] (ks0); issue A(t+1) 4x gload_lds; setprio1 MFMA32 setprio0
//   [s_barrier]
//   ph1: ds_read (ks1); issue B(t+1); MFMA32
// Loads for t+1 stay in flight across t's phases -> HBM never idles long.
__global__ __launch_bounds__(512, 2)
void gemm256_score_k(const unsigned short* __restrict__ Abf,
                     const unsigned short* __restrict__ Bw, int M,
                     const float* __restrict__ qb, const int* __restrict__ cl,
                     const float* __restrict__ Ws, float* __restrict__ out)
{
  // A tiles: bytes [0, 65536) (buf*32768); B tiles: bytes [65536, 131072)
  __shared__ unsigned short AB[65536];
  __shared__ float red[256][4];
  __shared__ int clds[256];

  const int t = threadIdx.x;
  const int lane = t & 63;
  const int w = t >> 6;                 // 0..7
  const int wr = w >> 2, wc = w & 3;
  const int l15 = lane & 15, l4 = lane >> 4;

  // bijective XCD-chunk swizzle (m204): works for any gridDim
  const int nwg = gridDim.x;
  {
  }
  int id;
  {
    int q = nwg >> 3, r = nwg & 7;
    int xcd = blockIdx.x & 7, pos = blockIdx.x >> 3;
    id = (xcd < r ? xcd * (q + 1) : r * (q + 1) + (xcd - r) * q) + pos;
  }
  const int n0 = (id & 1) * 256;        // N half fastest -> pairs share A panel in L2
  const int m0 = (id >> 1) * 256;

  if (t < 256) {
    int gm = m0 + t;
    clds[t] = (gm < M) ? cl[gm < M ? gm : M - 1] : cl[M - 1];
  }
  __builtin_amdgcn_sched_barrier(0);

  // ---- staging geometry: tile = 32 chunks of 1KB (8 rows x 128B); wave w owns
  // chunks w*4..w*4+3. lane: row-in-chunk = lane>>3, slot = lane&7;
  // source slot = (lane&7) ^ (row&7) = (lane&7) ^ (lane>>3).
  const int rin = lane >> 3;
  const int sl = lane & 7;
  const int sslot = sl ^ rin;

  const unsigned short* srcA[4];
  const unsigned short* srcB[4];
  int chunkOff[4];
  #pragma unroll
  for (int c = 0; c < 4; ++c) {
    int chunk = w * 4 + c;
    int rowA = m0 + chunk * 8 + rin; if (rowA > M - 1) rowA = M - 1;
    int colB = n0 + chunk * 8 + rin;           // always < 512
    srcA[c] = Abf + (size_t)rowA * 512 + sslot * 8;
    srcB[c] = Bw + (size_t)colB * 512 + sslot * 8;
    chunkOff[c] = chunk * 1024;
  }

  // ---- fragment read offsets (bytes within a 32KB tile buffer) ----
  // row part (ks-independent), slot part psk[ks] = ((ks*4+l4) ^ (l15&7)) * 16
  int rowA_off[8], rowB_off[4];
  #pragma unroll
  for (int mi = 0; mi < 8; ++mi) rowA_off[mi] = (wr * 128 + mi * 16 + l15) * 128;
  #pragma unroll
  for (int ni = 0; ni < 4; ++ni) rowB_off[ni] = (wc * 64 + ni * 16 + l15) * 128;
  int psk[2];
  psk[0] = ((l4) ^ (l15 & 7)) * 16;
  psk[1] = ((4 + l4) ^ (l15 & 7)) * 16;

  f32x4 acc[8][4];
  #pragma unroll
  for (int mi = 0; mi < 8; ++mi)
    #pragma unroll
    for (int ni = 0; ni < 4; ++ni)
      acc[mi][ni] = (f32x4){0.f, 0.f, 0.f, 0.f};

  // ---- prologue: issue tile 0 (A then B) into buffer 0 ----
  #pragma unroll
  for (int c = 0; c < 4; ++c)
    GLOAD_LDS16(srcA[c], ((char*)AB) + chunkOff[c]);
  #pragma unroll
  for (int c = 0; c < 4; ++c)
    GLOAD_LDS16(srcB[c], ((char*)AB) + 65536 + chunkOff[c]);
  __builtin_amdgcn_sched_barrier(0);

  #pragma unroll
  for (int kt = 0; kt < 8; ++kt) {
    const int buf = kt & 1;
    const char* Au = ((const char*)AB) + buf * 32768;
    const char* Bu = ((const char*)AB) + 65536 + buf * 32768;
    char* AuN = ((char*)AB) + (buf ^ 1) * 32768;
    char* BuN = ((char*)AB) + 65536 + (buf ^ 1) * 32768;

    // tile-top: tile kt's loads (issued during kt-1, >=1 phase ago) must land
    asm volatile("s_waitcnt vmcnt(0)" ::: "memory");
    __builtin_amdgcn_sched_barrier(0);
    __builtin_amdgcn_s_barrier();
    __builtin_amdgcn_sched_barrier(0);

    #pragma unroll
    for (int ks = 0; ks < 2; ++ks) {
      bf16x8 a[8], b[4];
      #pragma unroll
      for (int mi = 0; mi < 8; ++mi)
        a[mi] = *(const bf16x8*)(Au + rowA_off[mi] + psk[ks]);
      #pragma unroll
      for (int ni = 0; ni < 4; ++ni)
        b[ni] = *(const bf16x8*)(Bu + rowB_off[ni] + psk[ks]);

      // issue next tile's stages: ph0 -> A(kt+1), ph1 -> B(kt+1)
      if (kt < 7) {
        const int k1 = (kt + 1) * 64;     // element offset (+128B per tile)
        if (ks == 0) {
          #pragma unroll
          for (int c = 0; c < 4; ++c)
            GLOAD_LDS16(srcA[c] + k1, AuN + chunkOff[c]);
        } else {
          #pragma unroll
          for (int c = 0; c < 4; ++c)
            GLOAD_LDS16(srcB[c] + k1, BuN + chunkOff[c]);
        }
      }
      __builtin_amdgcn_sched_barrier(0);

      __builtin_amdgcn_s_setprio(1);
      #pragma unroll
      for (int mi = 0; mi < 8; ++mi)
        #pragma unroll
        for (int ni = 0; ni < 4; ++ni)
          acc[mi][ni] = __builtin_amdgcn_mfma_f32_16x16x32_bf16(a[mi], b[ni], acc[mi][ni], 0, 0, 0);
      __builtin_amdgcn_s_setprio(0);
      __builtin_amdgcn_sched_barrier(0);

      if (ks == 0) {                      // mid-tile alignment barrier
        __builtin_amdgcn_s_barrier();
        __builtin_amdgcn_sched_barrier(0);
      }
    }
  }

  // ---- epilogue: fused additive-attention partial score over 256 cols ----
  __syncthreads();
  #pragma unroll
  for (int mi = 0; mi < 8; ++mi) {
    #pragma unroll
    for (int r = 0; r < 4; ++r) {
      int rowt = wr * 128 + mi * 16 + l4 * 4 + r;
      int c = clds[rowt];
      const float* qrow = &qb[(size_t)c * 512];
      float s = 0.f;
      #pragma unroll
      for (int ni = 0; ni < 4; ++ni) {
        int gcol = n0 + wc * 64 + ni * 16 + l15;
        float x = acc[mi][ni][r] + qrow[gcol];
        s += tanh_fast(x) * Ws[gcol];
      }
      s += __shfl_xor(s, 1);
      s += __shfl_xor(s, 2);
      s += __shfl_xor(s, 4);
      s += __shfl_xor(s, 8);
      if (l15 == 0) red[rowt][wc] = s;
    }
  }
  __syncthreads();
  if (t < 256) {
    int gm = m0 + t;
    if (gm < M) atomicAdd(&out[gm], red[t][0] + red[t][1] + red[t][2] + red[t][3]);
  }
}

// --- bf16 MFMA GEMM: 128x128 tile, BK=32 (R5 kernel) -- used for the small GEMMs ---
template<int EPI>
__global__ __launch_bounds__(256)
void gemm128_k(const unsigned short* __restrict__ Abf,
               const unsigned short* __restrict__ Bw, int M,
               const float* __restrict__ bias, float* __restrict__ out)
{
  __shared__ unsigned short As[2][128 * 32];
  __shared__ unsigned short Bs[2][128 * 32];

  const int t = threadIdx.x;
  const int lane = t & 63;
  const int w = t >> 6;
  const int wr = w >> 1, wc = w & 1;
  const int l15 = lane & 15, l4 = lane >> 4;

  const int nwg = gridDim.x;
  int id = blockIdx.x;
  if ((nwg & 7) == 0) id = (id & 7) * (nwg >> 3) + (id >> 3);
  const int n0 = (id & 3) * 128;
  const int m0 = (id >> 2) * 128;

  const int rin = lane >> 2;
  const int sl = lane & 3;

  const unsigned short* srcA[2];
  const unsigned short* srcB[2];
  int dstOff[2];
  #pragma unroll
  for (int c = 0; c < 2; ++c) {
    int chunk = w * 2 + c;
    int row = chunk * 16 + rin;
    int slot = sl ^ ((row ^ (row >> 2)) & 3);
    int ga = m0 + row; if (ga > M - 1) ga = M - 1;
    srcA[c] = Abf + (size_t)ga * 512 + slot * 8;
    srcB[c] = Bw + (size_t)(n0 + row) * 512 + slot * 8;
    dstOff[c] = chunk * 1024;
  }

  int offA[4], offB[4];
  #pragma unroll
  for (int mi = 0; mi < 4; ++mi) {
    int row = wr * 64 + mi * 16 + l15;
    offA[mi] = row * 64 + ((l4 ^ ((row ^ (row >> 2)) & 3)) * 16);
  }
  #pragma unroll
  for (int ni = 0; ni < 4; ++ni) {
    int row = wc * 64 + ni * 16 + l15;
    offB[ni] = row * 64 + ((l4 ^ ((row ^ (row >> 2)) & 3)) * 16);
  }

  f32x4 acc[4][4];
  #pragma unroll
  for (int mi = 0; mi < 4; ++mi)
    #pragma unroll
    for (int ni = 0; ni < 4; ++ni)
      acc[mi][ni] = (f32x4){0.f, 0.f, 0.f, 0.f};

  #pragma unroll
  for (int c = 0; c < 2; ++c) {
    GLOAD_LDS16(srcA[c], ((char*)As[0]) + dstOff[c]);
    GLOAD_LDS16(srcB[c], ((char*)Bs[0]) + dstOff[c]);
  }
  __builtin_amdgcn_sched_barrier(0);

  #pragma unroll
  for (int it = 0; it < 16; ++it) {
    const int cur = it & 1;
    if (it < 15) {
      const int k1 = (it + 1) * 32;
      #pragma unroll
      for (int c = 0; c < 2; ++c) {
        GLOAD_LDS16(srcA[c] + k1, ((char*)As[cur ^ 1]) + dstOff[c]);
        GLOAD_LDS16(srcB[c] + k1, ((char*)Bs[cur ^ 1]) + dstOff[c]);
      }
      __builtin_amdgcn_sched_barrier(0);
      asm volatile("s_waitcnt vmcnt(4)" ::: "memory");
    } else {
      asm volatile("s_waitcnt vmcnt(0)" ::: "memory");
    }
    __builtin_amdgcn_sched_barrier(0);
    __builtin_amdgcn_s_barrier();
    __builtin_amdgcn_sched_barrier(0);

    {
      bf16x8 af[4], bfv[4];
      #pragma unroll
      for (int mi = 0; mi < 4; ++mi)
        af[mi] = *(const bf16x8*)(((const char*)As[cur]) + offA[mi]);
      #pragma unroll
      for (int ni = 0; ni < 4; ++ni)
        bfv[ni] = *(const bf16x8*)(((const char*)Bs[cur]) + offB[ni]);
      #pragma unroll
      for (int mi = 0; mi < 4; ++mi)
        #pragma unroll
        for (int ni = 0; ni < 4; ++ni)
          acc[mi][ni] = __builtin_amdgcn_mfma_f32_16x16x32_bf16(af[mi], bfv[ni], acc[mi][ni], 0, 0, 0);
    }
    __builtin_amdgcn_sched_barrier(0);
    __builtin_amdgcn_s_barrier();
    __builtin_amdgcn_sched_barrier(0);
  }

  #pragma unroll
  for (int mi = 0; mi < 4; ++mi) {
    #pragma unroll
    for (int r = 0; r < 4; ++r) {
      int gm = m0 + wr * 64 + mi * 16 + l4 * 4 + r;
      if (gm < M) {
        #pragma unroll
        for (int ni = 0; ni < 4; ++ni) {
          int gcol = n0 + wc * 64 + ni * 16 + l15;
          float v = acc[mi][ni][r] + bias[gcol];
          if (EPI == 2) v = tanh_fast(v);
          out[(size_t)gm * 512 + gcol] = v;
        }
      }
    }
  }
}

// ---------------- host side ----------------

extern "C" void kernel_launch(void* const* d_in, const int* in_sizes, int n_in,
                              void* d_out, int out_size, void* d_ws, size_t ws_size,
                              hipStream_t stream) {
  const float* h  = (const float*)d_in[0];
  const float* g  = (const float*)d_in[1];
  const int*   vn = (const int*)d_in[2];
  const int*   nid= (const int*)d_in[3];
  const float* Wq = (const float*)d_in[4];
  const float* Wk = (const float*)d_in[5];
  const float* ab = (const float*)d_in[6];
  const float* Ws = (const float*)d_in[7];
  const float* W  = (const float*)d_in[9];
  const float* b  = (const float*)d_in[10];

  const int B = in_sizes[3];          // 100000
  const int C = in_sizes[1] / D_DIM;  // 1000

  char* wsb = (char*)d_ws;
  size_t off = 0;
  auto alloc = [&](size_t bytes) -> void* {
    void* p = wsb + off;
    off += (bytes + 255) & ~(size_t)255;
    return p;
  };

  unsigned short* hbf   = (unsigned short*)alloc((size_t)B * 512 * 2);
  unsigned short* gbf   = (unsigned short*)alloc((size_t)C * 512 * 2);
  unsigned short* ctxbf = (unsigned short*)alloc((size_t)C * 512 * 2);
  unsigned short* Wk_bf = (unsigned short*)alloc((size_t)512 * 512 * 2);  // contiguous
  unsigned short* Wq_bf = (unsigned short*)alloc((size_t)512 * 512 * 2);  // with Wk_bf
  unsigned short* W_bf  = (unsigned short*)alloc((size_t)512 * 512 * 2);  // and Wq_bf
  float* qb    = (float*)alloc((size_t)C * 512 * 4);
  float* ctx   = (float*)alloc((size_t)C * 512 * 4);
  float* score = (float*)alloc((size_t)B * 4);
  float* ev    = (float*)alloc((size_t)B * 4);
  int*   cl    = (int*)alloc((size_t)B * 4);
  int*   order = (int*)alloc((size_t)B * 4);
  int*      counts = (int*)alloc((size_t)C * 4);
  unsigned* smax   = (unsigned*)alloc((size_t)C * 4);
  float*    denom  = (float*)alloc((size_t)C * 4);
  int* starts = (int*)alloc((size_t)(C + 1) * 4);
  int* cursor = (int*)alloc((size_t)C * 4);
  (void)ws_size; (void)n_in; (void)out_size;

  size_t zlen = (size_t)((char*)denom - (char*)counts) + (size_t)C * 4;
  hipMemsetAsync(counts, 0, zlen, stream);
  hipMemsetAsync(score, 0, (size_t)B * 4, stream);

  cvt_f32_bf16_k<<<(B * 512 / 4 + 255) / 256, 256, 0, stream>>>(h, hbf, B * 512 / 4);
  cvt_f32_bf16_k<<<(C * 512 / 4 + 255) / 256, 256, 0, stream>>>(g, gbf, C * 512 / 4);
  const int n4w = 512 * 512 / 4;
  cvt3_f32_bf16_k<<<(3 * n4w + 255) / 256, 256, 0, stream>>>(Wk, Wq, W, Wk_bf, n4w);

  prep_cluster_k<<<(B + 255) / 256, 256, 0, stream>>>(vn, nid, cl, counts, B);
  prefix_k<<<1, 1024, 0, stream>>>(counts, starts, cursor, C);
  scatter_k<<<(B + 255) / 256, 256, 0, stream>>>(cl, cursor, order, B);

  // qb = g @ Wq^T + attn_bias
  gemm128_k<0><<<4 * ((C + 127) / 128), 256, 0, stream>>>(gbf, Wq_bf, C, ab, qb);

  // score[m] += sum over this 256-col block of tanh(h@Wk^T + qb[cl])·Ws
  // (bs dropped: softmax invariant to constant shift)
  gemm256_score_k<<<2 * ((B + 255) / 256), 512, 0, stream>>>(
      hbf, Wk_bf, B, qb, cl, Ws, score);

  seg_max_k<<<(B + 255) / 256, 256, 0, stream>>>(score, cl, smax, B);
  seg_expsum_k<<<(B + 255) / 256, 256, 0, stream>>>(score, cl, smax, ev, denom, B);
  ctx_k<<<C, 256, 0, stream>>>(hbf, ev, order, starts, denom, ctx);

  cvt_f32_bf16_k<<<(C * 512 / 4 + 255) / 256, 256, 0, stream>>>(ctx, ctxbf, C * 512 / 4);

  // out = tanh(ctx @ W^T + b)
  gemm128_k<2><<<4 * ((C + 127) / 128), 256, 0, stream>>>(ctxbf, W_bf, C, b, (float*)d_out);
}